// Round 5
// baseline (3563.007 us; speedup 1.0000x reference)
//
#include <hip/hip_runtime.h>

#define NB 16
#define NC 256
#define NT 2048
#define NK 1024
#define TQB 128          // queries (t) per block
#define KCH 32           // codes per chunk (= MFMA N)
#define NCHUNKS 32       // NK / KCH
#define HALF_B 16384     // bytes of one (hi or lo) chunk: 32*256*2
#define CHUNK_B 32768    // hi+lo chunk bytes
#define AMB_TH 0.05f     // ambiguity margin >> bf16x3 error bound (~0.005)

typedef __attribute__((ext_vector_type(8))) short short8v;
typedef __attribute__((ext_vector_type(16))) float f32x16;

__device__ __forceinline__ unsigned bf16_rne(float x) {
  unsigned u = __float_as_uint(x);
  return (u + 0x7FFFu + ((u >> 16) & 1u)) >> 16;
}

// Prep: split codebook into bf16 hi/lo, stored pre-swizzled per 32-code chunk so
// linear global_load_lds staging lands in the XOR-swizzled LDS layout (m173 pattern).
// Also cnorm[k] = 0.5*||c_k||^2 (fp32 exact).
__global__ __launch_bounds__(256) void vq_prep(const float* __restrict__ cb,
                                               char* __restrict__ cbs,
                                               float* __restrict__ cnorm) {
  const int k = blockIdx.x, c = threadIdx.x;
  float v = cb[k * NC + c];
  unsigned hb = bf16_rne(v);
  float hf = __uint_as_float(hb << 16);
  unsigned lb = bf16_rne(v - hf);
  const int chunk = k >> 5, r = k & 31;
  // element (r,c) at byte r*512 + ((c>>3 ^ r)&31)*16 + (c&7)*2  (16B-slot XOR swizzle)
  const int off = (r << 9) + (((((c >> 3)) ^ r) & 31) << 4) + ((c & 7) << 1);
  *(unsigned short*)(cbs + (size_t)chunk * CHUNK_B + off) = (unsigned short)hb;
  *(unsigned short*)(cbs + (size_t)chunk * CHUNK_B + HALF_B + off) = (unsigned short)lb;
  float s = v * v;
  #pragma unroll
  for (int o = 32; o > 0; o >>= 1) s += __shfl_down(s, o, 64);
  __shared__ float wsum[4];
  if ((threadIdx.x & 63) == 0) wsum[threadIdx.x >> 6] = s;
  __syncthreads();
  if (threadIdx.x == 0) cnorm[k] = 0.5f * (wsum[0] + wsum[1] + wsum[2] + wsum[3]);
}

// Main: per block 128 queries (one b, 128 consecutive t), 4 waves x 32 q each.
// A (z hi/lo frags) resident in registers; B (codebook chunk) double-buffered in LDS.
// argmax of score = z.c - 0.5||c||^2 with sticky ambiguity flag.
__global__ __launch_bounds__(256, 1) void vq_main(const float* __restrict__ z,
                                                  const char* __restrict__ cbs,
                                                  const float* __restrict__ cnorm,
                                                  const float* __restrict__ cb,
                                                  float* __restrict__ out,
                                                  int* __restrict__ flags) {
  __shared__ char ldsb[2 * CHUNK_B];   // 64 KB double buffer
  __shared__ int idx_sh[TQB];
  __shared__ int amb_sh[TQB];
  const int tid = threadIdx.x;
  const int w = tid >> 6, l = tid & 63;
  const int r = l & 31;      // A row / B col / C col within 32x32 tile
  const int h = l >> 5;      // k-group half
  const int b = blockIdx.x >> 4;
  const int t0 = (blockIdx.x & 15) * TQB;
  const int tq = t0 + (w << 5) + r;    // this lane's query t

  // ---- load A (z) and split to bf16 hi/lo fragments: k=8h+e -> channel 16s+8h+e ----
  short8v Ahi[16], Alo[16];
  #pragma unroll
  for (int s = 0; s < 16; ++s) {
    const float* zp = z + ((size_t)(b * NC + (s << 4) + (h << 3))) * NT + tq;
    #pragma unroll
    for (int e = 0; e < 8; ++e) {
      float v = zp[(size_t)e * NT];
      unsigned hb = bf16_rne(v);
      float hf = __uint_as_float(hb << 16);
      unsigned lb = bf16_rne(v - hf);
      Ahi[s][e] = (short)hb;
      Alo[s][e] = (short)lb;
    }
  }

  float bestv[16];
  int besti[16];
  unsigned amb = 0u;
  #pragma unroll
  for (int i = 0; i < 16; ++i) { bestv[i] = -3.402823466e38f; besti[i] = 0; }

#define STAGE(CH, BSEL) do {                                                      \
    const char* _s = cbs + (size_t)(CH) * CHUNK_B + ((size_t)tid << 4);           \
    char* _d = ldsb + (BSEL) * CHUNK_B + (w << 10);                               \
    _Pragma("unroll")                                                             \
    for (int _j = 0; _j < 8; ++_j)                                                \
      __builtin_amdgcn_global_load_lds(                                           \
          (const __attribute__((address_space(1))) void*)(_s + (_j << 12)),       \
          (__attribute__((address_space(3))) void*)(_d + (_j << 12)), 16, 0, 0);  \
  } while (0)

  STAGE(0, 0);
  int bufsel = 0;
  for (int ch = 0; ch < NCHUNKS; ++ch) {
    STAGE((ch + 1) & (NCHUNKS - 1), bufsel ^ 1);        // prefetch next chunk
    asm volatile("s_waitcnt vmcnt(8)" ::: "memory");     // current chunk landed (this wave)
    __builtin_amdgcn_s_barrier();                        // ...and all other waves' quarters
    float cn = cnorm[(ch << 5) + r];
    f32x16 accA = {}, accB = {}, accC = {};              // 3 chains: hi*hi, hi*lo, lo*hi
    const char* Lh = ldsb + bufsel * CHUNK_B;
    #pragma unroll
    for (int s = 0; s < 16; ++s) {
      const int off = (r << 9) + (((((s << 1) + h) ^ r) & 31) << 4);
      short8v Bh = *(const short8v*)(Lh + off);
      short8v Bl = *(const short8v*)(Lh + HALF_B + off);
      accA = __builtin_amdgcn_mfma_f32_32x32x16_bf16(Ahi[s], Bh, accA, 0, 0, 0);
      accB = __builtin_amdgcn_mfma_f32_32x32x16_bf16(Ahi[s], Bl, accB, 0, 0, 0);
      accC = __builtin_amdgcn_mfma_f32_32x32x16_bf16(Alo[s], Bh, accC, 0, 0, 0);
    }
    __builtin_amdgcn_s_barrier();                        // done reading this buffer
    const int kidx = (ch << 5) + r;                      // C/D col = lane&31 (m101)
    #pragma unroll
    for (int i = 0; i < 16; ++i) {
      float sc = (accA[i] + accB[i] + accC[i]) - cn;
      float d = sc - bestv[i];
      amb |= (fabsf(d) <= AMB_TH) ? (1u << i) : 0u;      // sticky: near-tie seen
      if (d > 0.f) { bestv[i] = sc; besti[i] = kidx; }   // strict >, k ascending
    }
    bufsel ^= 1;
  }
#undef STAGE

  // ---- reduce over the 32 code-columns (lane bits 0..4; stays within h-half) ----
  #pragma unroll
  for (int st = 1; st < 32; st <<= 1) {
    #pragma unroll
    for (int i = 0; i < 16; ++i) {
      float ov = __shfl_xor(bestv[i], st, 64);
      int oi = __shfl_xor(besti[i], st, 64);
      // cross-lane near-tie must also flag (best/2nd-best in different lanes)
      amb |= (fabsf(ov - bestv[i]) <= AMB_TH) ? (1u << i) : 0u;
      if (ov > bestv[i] || (ov == bestv[i] && oi < besti[i])) { bestv[i] = ov; besti[i] = oi; }
    }
    amb |= __shfl_xor(amb, st, 64);
  }
  if (r == 0) {
    #pragma unroll
    for (int i = 0; i < 16; ++i) {
      const int row = (i & 3) + ((i >> 2) << 3) + (h << 2);   // m101 C/D row map
      idx_sh[(w << 5) + row] = besti[i];
      amb_sh[(w << 5) + row] = (amb >> i) & 1;
    }
  }
  asm volatile("s_waitcnt vmcnt(0)" ::: "memory");       // drain last prefetch
  __syncthreads();

  if (tid < TQB) {
    const int t = t0 + tid;
    out[(size_t)NB * NC * NT + (size_t)b * NT + t] = (float)idx_sh[tid];
    flags[b * NT + t] = amb_sh[tid];
  }

  // ---- gather epilogue: z_q[b][c][t] = cb[idx[t]][c], t-contiguous stores ----
  const int tt = tid & 127;
  const int chi = tid >> 7;
  const int myidx = idx_sh[tt];
  const float* crow = cb + (size_t)myidx * NC;
  const size_t obase = (size_t)b * NC * NT + (size_t)t0 + tt;
  #pragma unroll 8
  for (int c0 = 0; c0 < NC; c0 += 2) {
    const int c = c0 + chi;
    out[obase + (size_t)c * NT] = crow[c];
  }
}

// Cleanup: exact fp32 rescan for ambiguous queries (expected ~1%).
__global__ __launch_bounds__(256) void vq_cleanup(const float* __restrict__ z,
                                                  const float* __restrict__ cb,
                                                  const int* __restrict__ flags,
                                                  float* __restrict__ out) {
  __shared__ float zsh[NC];
  __shared__ unsigned long long red[5];
  __shared__ int anyflag;
  const int tid = threadIdx.x;
  const int b = blockIdx.x >> 4;
  const int t0 = (blockIdx.x & 15) * TQB;
  if (tid == 0) anyflag = 0;
  __syncthreads();
  if (tid < TQB && flags[b * NT + t0 + tid]) anyflag = 1;
  __syncthreads();
  if (!anyflag) return;
  for (int qq = 0; qq < TQB; ++qq) {
    if (!flags[b * NT + t0 + qq]) continue;   // uniform per block
    const int t = t0 + qq;
    zsh[tid] = z[((size_t)b * NC + tid) * NT + t];
    __syncthreads();
    float bd = 3.402823466e38f; int bi = NK;
    #pragma unroll
    for (int j = 0; j < 4; ++j) {
      const int k = (j << 8) + tid;           // ascending k per thread
      const float* ck = cb + (size_t)k * NC;
      float d0 = 0.f, d1 = 0.f, d2 = 0.f, d3 = 0.f;
      for (int c = 0; c < NC; c += 4) {
        float4 zz = *(const float4*)&zsh[c];
        float4 cc = *(const float4*)&ck[c];
        float e0 = zz.x - cc.x, e1 = zz.y - cc.y, e2 = zz.z - cc.z, e3 = zz.w - cc.w;
        d0 = fmaf(e0, e0, d0); d1 = fmaf(e1, e1, d1);
        d2 = fmaf(e2, e2, d2); d3 = fmaf(e3, e3, d3);
      }
      float d = (d0 + d1) + (d2 + d3);
      if (d < bd) { bd = d; bi = k; }
    }
    unsigned long long p = ((unsigned long long)__float_as_uint(bd) << 32) | (unsigned)bi;
    #pragma unroll
    for (int st = 1; st < 64; st <<= 1) {
      unsigned long long o = __shfl_xor(p, st, 64);
      if (o < p) p = o;
    }
    if ((tid & 63) == 0) red[tid >> 6] = p;
    __syncthreads();
    if (tid == 0) {
      unsigned long long m = red[0];
      for (int ww = 1; ww < 4; ++ww) if (red[ww] < m) m = red[ww];
      red[4] = m;
    }
    __syncthreads();
    const int best = (int)(red[4] & 0xFFFFFFFFull);
    if (tid == 0) out[(size_t)NB * NC * NT + (size_t)b * NT + t] = (float)best;
    out[((size_t)b * NC + tid) * NT + t] = cb[(size_t)best * NC + tid];
    __syncthreads();
  }
}

extern "C" void kernel_launch(void* const* d_in, const int* in_sizes, int n_in,
                              void* d_out, int out_size, void* d_ws, size_t ws_size,
                              hipStream_t stream) {
  const float* z = (const float*)d_in[0];
  const float* cb = (const float*)d_in[1];
  float* out = (float*)d_out;
  char* cbs = (char*)d_ws;                                            // 1 MB swizzled hi/lo
  float* cnorm = (float*)((char*)d_ws + (size_t)NCHUNKS * CHUNK_B);   // 4 KB
  int* flags = (int*)((char*)d_ws + (size_t)NCHUNKS * CHUNK_B + 4096);// 128 KB

  vq_prep<<<NK, NC, 0, stream>>>(cb, cbs, cnorm);
  vq_main<<<256, 256, 0, stream>>>(z, cbs, cnorm, cb, out, flags);
  vq_cleanup<<<256, 256, 0, stream>>>(z, cb, flags, out);
}

// Round 8
// 316.801 us; speedup vs baseline: 11.2468x; 11.2468x over previous
//
#include <hip/hip_runtime.h>

#define NB 16
#define NC 256
#define NT 2048
#define NK 1024
#define TQB 128          // queries (t) per block
#define NCHUNKS 32       // NK / 32
#define HALF_B 16384     // bytes of one (hi or lo) chunk: 32*256*2
#define CHUNK_B 32768    // hi+lo chunk bytes
#define AMB_TH 0.05f     // final top-2 gap threshold (>> bf16x3 error ~0.005)

typedef __attribute__((ext_vector_type(8))) short short8v;
typedef __attribute__((ext_vector_type(16))) float f32x16;

__device__ __forceinline__ unsigned bf16_rne(float x) {
  unsigned u = __float_as_uint(x);
  return (u + 0x7FFFu + ((u >> 16) & 1u)) >> 16;
}

// Prep: split codebook into bf16 hi/lo, stored pre-swizzled per 32-code chunk so
// linear global_load_lds staging lands in the XOR-swizzled LDS layout (m173 pattern).
// Also cnorm[k] = 0.5*||c_k||^2 (fp32 exact).
__global__ __launch_bounds__(256) void vq_prep(const float* __restrict__ cb,
                                               char* __restrict__ cbs,
                                               float* __restrict__ cnorm) {
  const int k = blockIdx.x, c = threadIdx.x;
  float v = cb[k * NC + c];
  unsigned hb = bf16_rne(v);
  float hf = __uint_as_float(hb << 16);
  unsigned lb = bf16_rne(v - hf);
  const int chunk = k >> 5, r = k & 31;
  // element (r,c) at byte r*512 + ((c>>3 ^ r)&31)*16 + (c&7)*2  (16B-slot XOR swizzle)
  const int off = (r << 9) + (((((c >> 3)) ^ r) & 31) << 4) + ((c & 7) << 1);
  *(unsigned short*)(cbs + (size_t)chunk * CHUNK_B + off) = (unsigned short)hb;
  *(unsigned short*)(cbs + (size_t)chunk * CHUNK_B + HALF_B + off) = (unsigned short)lb;
  float s = v * v;
  #pragma unroll
  for (int o = 32; o > 0; o >>= 1) s += __shfl_down(s, o, 64);
  __shared__ float wsum[4];
  if ((threadIdx.x & 63) == 0) wsum[threadIdx.x >> 6] = s;
  __syncthreads();
  if (threadIdx.x == 0) cnorm[k] = 0.5f * (wsum[0] + wsum[1] + wsum[2] + wsum[3]);
}

// Main: per block 128 queries (one b, 128 consecutive t), 4 waves x 32 q each.
// A (z hi/lo frags) in registers; B (codebook chunk) double-buffered in LDS.
// argmax of score = z.c - 0.5||c||^2 with exact top-2 gap tracking.
__global__ __launch_bounds__(256, 1) void vq_main(const float* __restrict__ z,
                                                  const char* __restrict__ cbs,
                                                  const float* __restrict__ cnorm,
                                                  const float* __restrict__ cb,
                                                  float* __restrict__ out,
                                                  int* __restrict__ flags) {
  __shared__ char ldsb[2 * CHUNK_B];   // 64 KB double buffer
  __shared__ int idx_sh[TQB];
  __shared__ int amb_sh[TQB];
  const int tid = threadIdx.x;
  const int w = tid >> 6, l = tid & 63;
  const int r = l & 31;      // A row / B col / C col within 32x32 tile
  const int h = l >> 5;      // k-group half
  const int b = blockIdx.x >> 4;
  const int t0 = (blockIdx.x & 15) * TQB;
  const int tq = t0 + (w << 5) + r;    // this lane's query t

  // ---- load A (z) and split to bf16 hi/lo fragments: k=8h+e -> channel 16s+8h+e ----
  short8v Ahi[16], Alo[16];
  #pragma unroll
  for (int s = 0; s < 16; ++s) {
    const float* zp = z + ((size_t)(b * NC + (s << 4) + (h << 3))) * NT + tq;
    #pragma unroll
    for (int e = 0; e < 8; ++e) {
      float v = zp[(size_t)e * NT];
      unsigned hb = bf16_rne(v);
      float hf = __uint_as_float(hb << 16);
      unsigned lb = bf16_rne(v - hf);
      Ahi[s][e] = (short)hb;
      Alo[s][e] = (short)lb;
    }
  }

  float bestv[16], secv[16];
  int besti[16];
  #pragma unroll
  for (int i = 0; i < 16; ++i) {
    bestv[i] = -3.402823466e38f; secv[i] = -3.402823466e38f; besti[i] = 0;
  }

#define STAGE(CH, BSEL) do {                                                      \
    const char* _s = cbs + (size_t)(CH) * CHUNK_B + ((size_t)tid << 4);           \
    char* _d = ldsb + (BSEL) * CHUNK_B + (w << 10);                               \
    _Pragma("unroll")                                                             \
    for (int _j = 0; _j < 8; ++_j)                                                \
      __builtin_amdgcn_global_load_lds(                                           \
          (const __attribute__((address_space(1))) void*)(_s + (_j << 12)),       \
          (__attribute__((address_space(3))) void*)(_d + (_j << 12)), 16, 0, 0);  \
  } while (0)

  STAGE(0, 0);
  int bufsel = 0;
  for (int ch = 0; ch < NCHUNKS; ++ch) {
    STAGE((ch + 1) & (NCHUNKS - 1), bufsel ^ 1);        // prefetch next chunk
    asm volatile("s_waitcnt vmcnt(8)" ::: "memory");     // current chunk landed (this wave)
    __builtin_amdgcn_s_barrier();                        // ...and all other waves' quarters
    float cn = cnorm[(ch << 5) + r];
    f32x16 accA = {}, accB = {}, accC = {};              // 3 chains: hi*hi, hi*lo, lo*hi
    const char* Lh = ldsb + bufsel * CHUNK_B;
    #pragma unroll
    for (int s = 0; s < 16; ++s) {
      const int off = (r << 9) + (((((s << 1) + h) ^ r) & 31) << 4);
      short8v Bh = *(const short8v*)(Lh + off);
      short8v Bl = *(const short8v*)(Lh + HALF_B + off);
      accA = __builtin_amdgcn_mfma_f32_32x32x16_bf16(Ahi[s], Bh, accA, 0, 0, 0);
      accB = __builtin_amdgcn_mfma_f32_32x32x16_bf16(Ahi[s], Bl, accB, 0, 0, 0);
      accC = __builtin_amdgcn_mfma_f32_32x32x16_bf16(Alo[s], Bh, accC, 0, 0, 0);
    }
    __builtin_amdgcn_s_barrier();                        // done reading this buffer
    const int kidx = (ch << 5) + r;                      // C/D col = lane&31 (m101)
    #pragma unroll
    for (int i = 0; i < 16; ++i) {
      float sc = (accA[i] + accB[i] + accC[i]) - cn;
      if (sc > bestv[i]) { secv[i] = bestv[i]; bestv[i] = sc; besti[i] = kidx; }
      else               { secv[i] = fmaxf(secv[i], sc); }   // ==best -> gap 0 -> flag
    }
    bufsel ^= 1;
  }
#undef STAGE

  // ---- top-2 merge over the 32 code-columns (lane bits 0..4; stays in h-half) ----
  #pragma unroll
  for (int st = 1; st < 32; st <<= 1) {
    #pragma unroll
    for (int i = 0; i < 16; ++i) {
      float ob = __shfl_xor(bestv[i], st, 64);
      float os = __shfl_xor(secv[i], st, 64);
      int   oi = __shfl_xor(besti[i], st, 64);
      if (ob > bestv[i]) {
        secv[i] = fmaxf(bestv[i], os);     // second of union = max(loser best, winner second)
        bestv[i] = ob; besti[i] = oi;
      } else {
        secv[i] = fmaxf(secv[i], ob);      // equal case -> secv = bestv -> gap 0 -> flagged
        if (ob == bestv[i] && oi < besti[i]) besti[i] = oi;  // first-index tie-break
      }
    }
  }
  if (r == 0) {
    #pragma unroll
    for (int i = 0; i < 16; ++i) {
      const int row = (i & 3) + ((i >> 2) << 3) + (h << 2);   // m101 C/D row map
      idx_sh[(w << 5) + row] = besti[i];
      amb_sh[(w << 5) + row] = (bestv[i] - secv[i] <= AMB_TH) ? 1 : 0;
    }
  }
  asm volatile("s_waitcnt vmcnt(0)" ::: "memory");       // drain last prefetch
  __syncthreads();

  if (tid < TQB) {
    const int t = t0 + tid;
    out[(size_t)NB * NC * NT + (size_t)b * NT + t] = (float)idx_sh[tid];
    flags[b * NT + t] = amb_sh[tid];
  }

  // ---- gather epilogue: z_q[b][c][t] = cb[idx[t]][c], t-contiguous stores ----
  const int tt = tid & 127;
  const int chi = tid >> 7;
  const int myidx = idx_sh[tt];
  const float* crow = cb + (size_t)myidx * NC;
  const size_t obase = (size_t)b * NC * NT + (size_t)t0 + tt;
  #pragma unroll 8
  for (int c0 = 0; c0 < NC; c0 += 2) {
    const int c = c0 + chi;
    out[obase + (size_t)c * NT] = crow[c];
  }
}

// Cleanup: exact fp32 rescan, ONE BLOCK PER QUERY, early-exit if not flagged.
__global__ __launch_bounds__(256) void vq_cleanup(const float* __restrict__ z,
                                                  const float* __restrict__ cb,
                                                  const int* __restrict__ flags,
                                                  float* __restrict__ out) {
  const int q = blockIdx.x;           // 0 .. NB*NT-1
  if (!flags[q]) return;              // block-uniform early exit
  const int b = q >> 11, t = q & (NT - 1);
  __shared__ float zsh[NC];
  __shared__ unsigned long long red[5];
  const int tid = threadIdx.x;
  zsh[tid] = z[((size_t)b * NC + tid) * NT + t];
  __syncthreads();
  float bd = 3.402823466e38f; int bi = NK;
  #pragma unroll
  for (int j = 0; j < 4; ++j) {
    const int k = (j << 8) + tid;     // ascending k per thread
    const float* ck = cb + (size_t)k * NC;
    float d0 = 0.f, d1 = 0.f, d2 = 0.f, d3 = 0.f;
    for (int c = 0; c < NC; c += 4) {
      float4 zz = *(const float4*)&zsh[c];
      float4 cc = *(const float4*)&ck[c];
      float e0 = zz.x - cc.x, e1 = zz.y - cc.y, e2 = zz.z - cc.z, e3 = zz.w - cc.w;
      d0 = fmaf(e0, e0, d0); d1 = fmaf(e1, e1, d1);
      d2 = fmaf(e2, e2, d2); d3 = fmaf(e3, e3, d3);
    }
    float d = (d0 + d1) + (d2 + d3);
    if (d < bd) { bd = d; bi = k; }
  }
  unsigned long long p = ((unsigned long long)__float_as_uint(bd) << 32) | (unsigned)bi;
  #pragma unroll
  for (int st = 1; st < 64; st <<= 1) {
    unsigned long long o = __shfl_xor(p, st, 64);
    if (o < p) p = o;
  }
  if ((tid & 63) == 0) red[tid >> 6] = p;
  __syncthreads();
  if (tid == 0) {
    unsigned long long m = red[0];
    for (int ww = 1; ww < 4; ++ww) if (red[ww] < m) m = red[ww];
    red[4] = m;
  }
  __syncthreads();
  const int best = (int)(red[4] & 0xFFFFFFFFull);
  if (tid == 0) out[(size_t)NB * NC * NT + (size_t)b * NT + t] = (float)best;
  out[((size_t)b * NC + tid) * NT + t] = cb[(size_t)best * NC + tid];
}

extern "C" void kernel_launch(void* const* d_in, const int* in_sizes, int n_in,
                              void* d_out, int out_size, void* d_ws, size_t ws_size,
                              hipStream_t stream) {
  const float* z = (const float*)d_in[0];
  const float* cb = (const float*)d_in[1];
  float* out = (float*)d_out;
  char* cbs = (char*)d_ws;                                            // 1 MB swizzled hi/lo
  float* cnorm = (float*)((char*)d_ws + (size_t)NCHUNKS * CHUNK_B);   // 4 KB
  int* flags = (int*)((char*)d_ws + (size_t)NCHUNKS * CHUNK_B + 4096);// 128 KB

  vq_prep<<<NK, NC, 0, stream>>>(cb, cbs, cnorm);
  vq_main<<<256, 256, 0, stream>>>(z, cbs, cnorm, cb, out, flags);
  vq_cleanup<<<NB * NT, 256, 0, stream>>>(z, cb, flags, out);
}